// Round 1
// 555.745 us; speedup vs baseline: 1.1358x; 1.1358x over previous
//
#include <hip/hip_runtime.h>
#include <hip/hip_fp16.h>
#include <math.h>
#include <float.h>
#include <stdint.h>

#define NN 100000
#define NE 1600000

#define SCAN_T 256
#define SCAN_E 1024
#define SCAN_NB ((NN + SCAN_E - 1) / SCAN_E)   // 98

#define NBUCK ((NN + 255) / 256)               // 391 buckets of 256 dsts
#define EPB   4096                              // edges per binning block
#define NBLK  ((NE + EPB - 1) / EPB)            // 391 binning blocks
#define HISTN (NBUCK * NBLK)                    // 152,881
#define GS_NB ((HISTN + SCAN_E - 1) / SCAN_E)   // 150
#define BCAP  5120                              // per-bucket LDS sort capacity

typedef __attribute__((ext_vector_type(8))) short short8v;
typedef __attribute__((ext_vector_type(4))) float float4v;

// ---------------- bf16 split helpers (RNE) ----------------
__device__ __forceinline__ unsigned short f32_to_bf16_rne(float f) {
    unsigned u = __float_as_uint(f);
    u += 0x7FFFu + ((u >> 16) & 1u);
    return (unsigned short)(u >> 16);
}
__device__ __forceinline__ float bf16_to_f32(unsigned short h) {
    return __uint_as_float(((unsigned)h) << 16);
}

// ---------------- W pre-split into MFMA B-fragment layout ----------------
// layout: per (ct, ks) cell of 1024 ushort: [hi: 64 lanes x 8][lo: 64 lanes x 8]
// lane l of a wave holds B[k = ks*32 + (l>>4)*8 + j][col = ct*16 + (l&15)]
template<int K, int OUT>
__global__ __launch_bounds__(256)
void prep_w(const float* __restrict__ Wq, const float* __restrict__ Wk,
            const float* __restrict__ Wv, const float* __restrict__ Ws,
            unsigned short* __restrict__ wsp) {
    constexpr int NKS  = (K + 31) / 32;
    constexpr int OUTT = 4 * OUT;
    constexpr int NCT  = OUTT / 16;
    int idx = blockIdx.x * 256 + threadIdx.x;
    if (idx >= NCT * NKS * 512) return;
    int j    = idx & 7;
    int lane = (idx >> 3) & 63;
    int cell = idx >> 9;            // ct*NKS + ks
    int ks   = cell % NKS;
    int ct   = cell / NKS;
    int g = lane >> 4, ln = lane & 15;
    int k = ks * 32 + g * 8 + j;
    int c = ct * 16 + ln;
    int mat = c / OUT, cm = c % OUT;
    const float* W = (mat == 0) ? Wq : (mat == 1) ? Wk : (mat == 2) ? Wv : Ws;
    float f = (k < K) ? W[(size_t)k * OUT + cm] : 0.f;
    unsigned short h = f32_to_bf16_rne(f);
    float resid = f - bf16_to_f32(h);
    wsp[(size_t)cell * 1024 + lane * 8 + j]       = h;
    wsp[(size_t)cell * 1024 + 512 + lane * 8 + j] = f32_to_bf16_rne(resid);
}

// ---------------- fused linear via bf16x3 MFMA ----------------
// Y[N x 4*OUT] = X[N x K] @ [Wq|Wk|Wv|Ws] + bias, routed to q (f32), kv (f16
// packed), outskip (f32). x split into bf16 hi/lo on the fly; per column tile
// acc = Ahi*Blo + Alo*Bhi + Ahi*Bhi (fp32 accum) -> error ~2^-16 relative.
template<int K, int OUT, int CTSPLIT>
__global__ __launch_bounds__(256)
void gemm_qkvs(const float* __restrict__ x,
               const unsigned short* __restrict__ wsp,
               const float* __restrict__ bq, const float* __restrict__ bk,
               const float* __restrict__ bv, const float* __restrict__ bs,
               float* __restrict__ q, unsigned short* __restrict__ kv,
               float* __restrict__ outskip) {
    constexpr int NKS  = (K + 31) / 32;
    constexpr int OUTT = 4 * OUT;
    constexpr int NCT  = OUTT / 16;
    constexpr int CTPB = NCT / CTSPLIT;

    const int t    = threadIdx.x;
    const int lane = t & 63;
    const int wv   = t >> 6;
    const int g    = lane >> 4;
    const int ln   = lane & 15;
    const int rowbase = (blockIdx.x * 4 + wv) * 32;
    if (rowbase >= NN) return;    // no barriers in this kernel

    union F8 { short8v v; unsigned short s[8]; uint4 u4; };

    // ---- load + split A fragments: 2 row-tiles of 16, K along lane>>4 ----
    F8 ahi[2][NKS], alo[2][NKS];
#pragma unroll
    for (int rt = 0; rt < 2; ++rt) {
        int r = rowbase + rt * 16 + ln;
        if (r >= NN) r = NN - 1;                 // stores are guarded
        const float* rowp = x + (size_t)r * K;
#pragma unroll
        for (int ks = 0; ks < NKS; ++ks) {
            const int k0 = ks * 32 + g * 8;
            float xv[8];
            if (k0 + 8 <= K) {
                float4 p0 = *(const float4*)(rowp + k0);
                float4 p1 = *(const float4*)(rowp + k0 + 4);
                xv[0] = p0.x; xv[1] = p0.y; xv[2] = p0.z; xv[3] = p0.w;
                xv[4] = p1.x; xv[5] = p1.y; xv[6] = p1.z; xv[7] = p1.w;
            } else {
#pragma unroll
                for (int j = 0; j < 8; ++j) xv[j] = 0.f;   // K=8 zero-pad
            }
#pragma unroll
            for (int j = 0; j < 8; ++j) {
                unsigned short h = f32_to_bf16_rne(xv[j]);
                ahi[rt][ks].s[j] = h;
                alo[rt][ks].s[j] = f32_to_bf16_rne(xv[j] - bf16_to_f32(h));
            }
        }
    }

    const int ct0 = blockIdx.y * CTPB;
#pragma unroll 1
    for (int ct = ct0; ct < ct0 + CTPB; ++ct) {
        // ---- B fragments: coalesced 16B/lane, L1-resident across blocks ----
        F8 bhi[NKS], blo[NKS];
        const unsigned short* wp = wsp + (size_t)(ct * NKS) * 1024 + lane * 8;
#pragma unroll
        for (int ks = 0; ks < NKS; ++ks) {
            bhi[ks].u4 = *(const uint4*)(wp + ks * 1024);
            blo[ks].u4 = *(const uint4*)(wp + ks * 1024 + 512);
        }

        const int cb  = ct * 16;
        const int mat = cb / OUT;                // wave-uniform
        const int cm  = (cb % OUT) + ln;
        const float* B = (mat == 0) ? bq : (mat == 1) ? bk : (mat == 2) ? bv : bs;
        const float bias = B[cm];
        float4v acc0 = {bias, bias, bias, bias};
        float4v acc1 = {bias, bias, bias, bias};
#pragma unroll
        for (int ks = 0; ks < NKS; ++ks) {
            acc0 = __builtin_amdgcn_mfma_f32_16x16x32_bf16(ahi[0][ks].v, blo[ks].v, acc0, 0, 0, 0);
            acc0 = __builtin_amdgcn_mfma_f32_16x16x32_bf16(alo[0][ks].v, bhi[ks].v, acc0, 0, 0, 0);
            acc0 = __builtin_amdgcn_mfma_f32_16x16x32_bf16(ahi[0][ks].v, bhi[ks].v, acc0, 0, 0, 0);
            acc1 = __builtin_amdgcn_mfma_f32_16x16x32_bf16(ahi[1][ks].v, blo[ks].v, acc1, 0, 0, 0);
            acc1 = __builtin_amdgcn_mfma_f32_16x16x32_bf16(alo[1][ks].v, bhi[ks].v, acc1, 0, 0, 0);
            acc1 = __builtin_amdgcn_mfma_f32_16x16x32_bf16(ahi[1][ks].v, bhi[ks].v, acc1, 0, 0, 0);
        }

        // ---- epilogue: D row = (lane>>4)*4 + reg, col = lane&15 (HW-verified) ----
        if (mat == 0 || mat == 3) {
            float* dst = (mat == 0) ? q : outskip;
#pragma unroll
            for (int rt = 0; rt < 2; ++rt) {
                float4v a = rt ? acc1 : acc0;
#pragma unroll
                for (int reg = 0; reg < 4; ++reg) {
                    int node = rowbase + rt * 16 + g * 4 + reg;
                    if (node < NN)
                        dst[(size_t)node * OUT + cm] = a[reg];
                }
            }
        } else {
            const int base = (mat == 1) ? 0 : OUT;   // k block then v block
#pragma unroll
            for (int rt = 0; rt < 2; ++rt) {
                float4v a = rt ? acc1 : acc0;
#pragma unroll
                for (int reg = 0; reg < 4; ++reg) {
                    int node = rowbase + rt * 16 + g * 4 + reg;
                    float f = a[reg];
                    float other = __shfl_xor(f, 1);  // pair adjacent columns
                    if (node < NN && !(ln & 1)) {
                        unsigned lo16 = __half_as_ushort(__float2half_rn(f));
                        unsigned hi16 = __half_as_ushort(__float2half_rn(other));
                        *(unsigned*)(kv + (size_t)node * (2 * OUT) + base + cm)
                            = lo16 | (hi16 << 16);
                    }
                }
            }
        }
    }
}

// ---------------- deterministic radix partition by dst>>8 (unchanged) ----------------
__global__ __launch_bounds__(256)
void bin_count(const int* __restrict__ ei, int* __restrict__ hist) {
    __shared__ int h[NBUCK];
    const int t = threadIdx.x;
    for (int i = t; i < NBUCK; i += 256) h[i] = 0;
    __syncthreads();
    int e0 = blockIdx.x * EPB;
    int e1 = e0 + EPB < NE ? e0 + EPB : NE;
    for (int i = e0 + t; i < e1; i += 256)
        atomicAdd(&h[ei[NE + i] >> 8], 1);
    __syncthreads();
    for (int i = t; i < NBUCK; i += 256)
        hist[(size_t)i * NBLK + blockIdx.x] = h[i];
}

__global__ __launch_bounds__(SCAN_T)
void gscan1(int* __restrict__ a, int* __restrict__ bsums) {
    __shared__ int lds[SCAN_T];
    int t = threadIdx.x;
    int base = blockIdx.x * SCAN_E + t * 4;
    int vals[4];
    int s = 0;
#pragma unroll
    for (int j = 0; j < 4; ++j) {
        int idx = base + j;
        vals[j] = (idx < HISTN) ? a[idx] : 0;
        s += vals[j];
    }
    lds[t] = s;
    __syncthreads();
    for (int off = 1; off < SCAN_T; off <<= 1) {
        int xx = (t >= off) ? lds[t - off] : 0;
        __syncthreads();
        lds[t] += xx;
        __syncthreads();
    }
    int run = (t > 0) ? lds[t - 1] : 0;
    if (t == SCAN_T - 1) bsums[blockIdx.x] = lds[t];
#pragma unroll
    for (int j = 0; j < 4; ++j) {
        int idx = base + j;
        if (idx < HISTN) a[idx] = run;
        run += vals[j];
    }
}

__global__ __launch_bounds__(256)
void gscan2(int* __restrict__ bsums) {
    __shared__ int lds[256];
    int t = threadIdx.x;
    lds[t] = (t < GS_NB) ? bsums[t] : 0;
    __syncthreads();
    for (int off = 1; off < 256; off <<= 1) {
        int xx = (t >= off) ? lds[t - off] : 0;
        __syncthreads();
        lds[t] += xx;
        __syncthreads();
    }
    if (t < GS_NB) bsums[t] = (t > 0) ? lds[t - 1] : 0;
}

__global__ __launch_bounds__(256)
void gscan3(int* __restrict__ a, const int* __restrict__ bsums,
            int* __restrict__ bstart) {
    int i = blockIdx.x * 256 + threadIdx.x;
    if (i < HISTN) {
        int v = a[i] + bsums[i / SCAN_E];
        a[i] = v;
        if (i % NBLK == 0) bstart[i / NBLK] = v;
    }
    if (i == 0) bstart[NBUCK] = NE;
}

__global__ __launch_bounds__(256)
void bin_scatter(const int* __restrict__ ei, const int* __restrict__ hist,
                 unsigned* __restrict__ ebuf) {
    __shared__ int off[NBUCK];
    const int t = threadIdx.x;
    for (int i = t; i < NBUCK; i += 256)
        off[i] = hist[(size_t)i * NBLK + blockIdx.x];
    __syncthreads();
    int e0 = blockIdx.x * EPB;
    int e1 = e0 + EPB < NE ? e0 + EPB : NE;
    for (int i = e0 + t; i < e1; i += 256) {
        int src = ei[i];
        int dst = ei[NE + i];
        int b = dst >> 8;
        int p = atomicAdd(&off[b], 1);
        ebuf[p] = ((unsigned)(dst & 255) << 17) | (unsigned)src;
    }
}

__global__ __launch_bounds__(256)
void bucket_hist(const int* __restrict__ bstart,
                 const unsigned* __restrict__ ebuf,
                 int* __restrict__ counts) {
    __shared__ int h[256];
    const int b = blockIdx.x;
    const int t = threadIdx.x;
    h[t] = 0;
    __syncthreads();
    int beg = bstart[b], end = bstart[b + 1];
    for (int i = beg + t; i < end; i += 256)
        atomicAdd(&h[ebuf[i] >> 17], 1);
    __syncthreads();
    int d = b * 256 + t;
    if (d < NN) counts[d] = h[t];
}

__global__ __launch_bounds__(SCAN_T)
void scan1(const int* __restrict__ counts, int* __restrict__ offsets,
           int* __restrict__ blocksums) {
    __shared__ int lds[SCAN_T];
    int t = threadIdx.x;
    int base = blockIdx.x * SCAN_E + t * 4;
    int vals[4];
    int s = 0;
#pragma unroll
    for (int j = 0; j < 4; ++j) {
        int idx = base + j;
        vals[j] = (idx < NN) ? counts[idx] : 0;
        s += vals[j];
    }
    lds[t] = s;
    __syncthreads();
    for (int off = 1; off < SCAN_T; off <<= 1) {
        int xx = (t >= off) ? lds[t - off] : 0;
        __syncthreads();
        lds[t] += xx;
        __syncthreads();
    }
    int run = (t > 0) ? lds[t - 1] : 0;
    if (t == SCAN_T - 1) blocksums[blockIdx.x] = lds[t];
#pragma unroll
    for (int j = 0; j < 4; ++j) {
        int idx = base + j;
        if (idx < NN) offsets[idx] = run;
        run += vals[j];
    }
}

__global__ __launch_bounds__(128)
void scan2(int* __restrict__ blocksums) {
    __shared__ int lds[128];
    int t = threadIdx.x;
    lds[t] = (t < SCAN_NB) ? blocksums[t] : 0;
    __syncthreads();
    for (int off = 1; off < 128; off <<= 1) {
        int xx = (t >= off) ? lds[t - off] : 0;
        __syncthreads();
        lds[t] += xx;
        __syncthreads();
    }
    if (t < SCAN_NB) blocksums[t] = (t > 0) ? lds[t - 1] : 0;
}

__global__ __launch_bounds__(256)
void scan3(int* __restrict__ offsets, const int* __restrict__ blocksums) {
    int i = blockIdx.x * blockDim.x + threadIdx.x;
    if (i < NN) offsets[i] = offsets[i] + blocksums[i / SCAN_E];
    if (i == 0) offsets[NN] = NE;
}

__global__ __launch_bounds__(256)
void csr_write(const int* __restrict__ bstart,
               const unsigned* __restrict__ ebuf,
               const int* __restrict__ offsets,
               int* __restrict__ sorted_src) {
    __shared__ int h[256];
    __shared__ int pre[256];
    __shared__ int posi[256];
    __shared__ unsigned srt[BCAP];
    const int b = blockIdx.x;
    const int t = threadIdx.x;
    h[t] = 0;
    __syncthreads();
    int beg = bstart[b];
    int cnt = bstart[b + 1] - beg;
    cnt = cnt < BCAP ? cnt : BCAP;
    const unsigned* buf = ebuf + beg;
    for (int i = t; i < cnt; i += 256)
        atomicAdd(&h[buf[i] >> 17], 1);
    __syncthreads();
    int v = h[t];
    pre[t] = v;
    __syncthreads();
    for (int off = 1; off < 256; off <<= 1) {
        int xx = (t >= off) ? pre[t - off] : 0;
        __syncthreads();
        pre[t] += xx;
        __syncthreads();
    }
    posi[t] = pre[t] - v;
    __syncthreads();
    for (int i = t; i < cnt; i += 256) {
        unsigned u = buf[i];
        int dl = u >> 17;
        int p = atomicAdd(&posi[dl], 1);
        srt[p] = u & 0x1FFFFu;
    }
    __syncthreads();
    const int base = offsets[b << 8];
    for (int i = t; i < cnt; i += 256)
        sorted_src[base + i] = (int)srt[i];
}

// ---- 16-lane row sum via DPP rotates ----
__device__ __forceinline__ float row16_sum(float x) {
    int y;
    y = __builtin_amdgcn_update_dpp(0, __float_as_int(x), 0x121, 0xF, 0xF, true); x += __int_as_float(y);
    y = __builtin_amdgcn_update_dpp(0, __float_as_int(x), 0x122, 0xF, 0xF, true); x += __int_as_float(y);
    y = __builtin_amdgcn_update_dpp(0, __float_as_int(x), 0x124, 0xF, 0xF, true); x += __int_as_float(y);
    y = __builtin_amdgcn_update_dpp(0, __float_as_int(x), 0x128, 0xF, 0xF, true); x += __int_as_float(y);
    return x;
}

__device__ __forceinline__ float4 h4_to_f4(uint2 w) {
    union { unsigned u; __half2 h; } a, b;
    a.u = w.x; b.u = w.y;
    float2 f0 = __half22float2(a.h);
    float2 f1 = __half22float2(b.h);
    return make_float4(f0.x, f0.y, f1.x, f1.y);
}

// ---------------- fused attention gather (unchanged) ----------------
template<int C, bool RELU>
__global__ __launch_bounds__(256)
void attn_gather(const int* __restrict__ offsets,
                 const int* __restrict__ sorted_src,
                 const float* __restrict__ q,
                 const unsigned short* __restrict__ kv,
                 float* __restrict__ out, float scale) {
    const int wid  = (int)((blockIdx.x * blockDim.x + threadIdx.x) >> 6);
    const int lane = threadIdx.x & 63;
    if (wid >= NN) return;
    const int grp = lane >> 4;
    const int ch  = (lane & 15) * 4;
    constexpr bool P2 = (C > 64);
    const bool hi = P2 && (ch + 64 < C);

    const int beg = offsets[wid], end = offsets[wid + 1];

    float4 qv0 = *(const float4*)(q + (size_t)wid * C + ch);
    float4 qv1 = make_float4(0.f, 0.f, 0.f, 0.f);
    if (hi) qv1 = *(const float4*)(q + (size_t)wid * C + ch + 64);

    float m = -FLT_MAX, l = 0.f;
    float4 a0 = make_float4(0.f, 0.f, 0.f, 0.f);
    float4 a1 = make_float4(0.f, 0.f, 0.f, 0.f);

    int i = beg + grp;
    uint2 kw0 = make_uint2(0, 0), vw0 = kw0, kw1 = kw0, vw1 = kw0;
    if (i < end) {
        const unsigned short* row = kv + (size_t)sorted_src[i] * (2 * C);
        kw0 = *(const uint2*)(row + ch);
        vw0 = *(const uint2*)(row + C + ch);
        if (hi) {
            kw1 = *(const uint2*)(row + 64 + ch);
            vw1 = *(const uint2*)(row + C + 64 + ch);
        }
    }
    while (i < end) {
        int inext = i + 4;
        uint2 nkw0 = make_uint2(0, 0), nvw0 = nkw0, nkw1 = nkw0, nvw1 = nkw0;
        if (inext < end) {
            const unsigned short* row = kv + (size_t)sorted_src[inext] * (2 * C);
            nkw0 = *(const uint2*)(row + ch);
            nvw0 = *(const uint2*)(row + C + ch);
            if (hi) {
                nkw1 = *(const uint2*)(row + 64 + ch);
                nvw1 = *(const uint2*)(row + C + 64 + ch);
            }
        }
        float4 kf0 = h4_to_f4(kw0);
        float4 vf0 = h4_to_f4(vw0);
        float part = qv0.x * kf0.x + qv0.y * kf0.y + qv0.z * kf0.z + qv0.w * kf0.w;
        float4 kf1, vf1;
        if (P2) {
            kf1 = h4_to_f4(kw1);
            vf1 = h4_to_f4(vw1);
            part += qv1.x * kf1.x + qv1.y * kf1.y + qv1.z * kf1.z + qv1.w * kf1.w;
        }
        float s = row16_sum(part) * scale;
        float mn = fmaxf(m, s);
        float al = __expf(m - mn);
        float w  = __expf(s - mn);
        l = l * al + w;
        a0.x = a0.x * al + w * vf0.x; a0.y = a0.y * al + w * vf0.y;
        a0.z = a0.z * al + w * vf0.z; a0.w = a0.w * al + w * vf0.w;
        if (P2) {
            a1.x = a1.x * al + w * vf1.x; a1.y = a1.y * al + w * vf1.y;
            a1.z = a1.z * al + w * vf1.z; a1.w = a1.w * al + w * vf1.w;
        }
        m = mn;
        kw0 = nkw0; vw0 = nvw0; kw1 = nkw1; vw1 = nvw1;
        i = inext;
    }

#pragma unroll
    for (int d = 16; d <= 32; d <<= 1) {
        float mo = __shfl_xor(m, d);
        float lo = __shfl_xor(l, d);
        float4 ao0, ao1;
        ao0.x = __shfl_xor(a0.x, d); ao0.y = __shfl_xor(a0.y, d);
        ao0.z = __shfl_xor(a0.z, d); ao0.w = __shfl_xor(a0.w, d);
        if (P2) {
            ao1.x = __shfl_xor(a1.x, d); ao1.y = __shfl_xor(a1.y, d);
            ao1.z = __shfl_xor(a1.z, d); ao1.w = __shfl_xor(a1.w, d);
        }
        float mn = fmaxf(m, mo);
        float e1 = (l  > 0.f) ? __expf(m  - mn) : 0.f;
        float e2 = (lo > 0.f) ? __expf(mo - mn) : 0.f;
        l = l * e1 + lo * e2;
        a0.x = a0.x * e1 + ao0.x * e2; a0.y = a0.y * e1 + ao0.y * e2;
        a0.z = a0.z * e1 + ao0.z * e2; a0.w = a0.w * e1 + ao0.w * e2;
        if (P2) {
            a1.x = a1.x * e1 + ao1.x * e2; a1.y = a1.y * e1 + ao1.y * e2;
            a1.z = a1.z * e1 + ao1.z * e2; a1.w = a1.w * e1 + ao1.w * e2;
        }
        m = mn;
    }

    if (lane < 16) {
        float inv = (l > 0.f) ? 1.f / l : 0.f;
        size_t o = (size_t)wid * C + ch;
        float4 sk = *(const float4*)(out + o);
        float4 r;
        r.x = sk.x + a0.x * inv; r.y = sk.y + a0.y * inv;
        r.z = sk.z + a0.z * inv; r.w = sk.w + a0.w * inv;
        if (RELU) {
            r.x = fmaxf(r.x, 0.f); r.y = fmaxf(r.y, 0.f);
            r.z = fmaxf(r.z, 0.f); r.w = fmaxf(r.w, 0.f);
        }
        *(float4*)(out + o) = r;
        if (hi) {
            float4 sk1 = *(const float4*)(out + o + 64);
            float4 r1;
            r1.x = sk1.x + a1.x * inv; r1.y = sk1.y + a1.y * inv;
            r1.z = sk1.z + a1.z * inv; r1.w = sk1.w + a1.w * inv;
            if (RELU) {
                r1.x = fmaxf(r1.x, 0.f); r1.y = fmaxf(r1.y, 0.f);
                r1.z = fmaxf(r1.z, 0.f); r1.w = fmaxf(r1.w, 0.f);
            }
            *(float4*)(out + o + 64) = r1;
        }
    }
}

// ---------------- host side ----------------
template<int K, int OUT, bool RELU>
static void run_layer(const float* xin, const unsigned short* wsp,
                      const float* const* Wb,
                      const int* offsets, const int* sorted_src,
                      float* q, unsigned short* kv,
                      float* out, hipStream_t stream) {
    constexpr int CTSPLIT = 2;
    dim3 gg((NN + 127) / 128, CTSPLIT);
    gemm_qkvs<K, OUT, CTSPLIT><<<gg, 256, 0, stream>>>(
        xin, wsp, Wb[1], Wb[3], Wb[5], Wb[7], q, kv, out);

    float scale = 1.0f / sqrtf((float)OUT);
    attn_gather<OUT, RELU><<<(NN + 3) / 4, 256, 0, stream>>>(
        offsets, sorted_src, q, kv, out, scale);
}

extern "C" void kernel_launch(void* const* d_in, const int* in_sizes, int n_in,
                              void* d_out, int out_size, void* d_ws, size_t ws_size,
                              hipStream_t stream) {
    const float* x  = (const float*)d_in[0];
    const int*   ei = (const int*)d_in[1];
    const float* Wb0[8], *Wb1[8], *Wb2[8];
    for (int i = 0; i < 8; ++i) {
        Wb0[i] = (const float*)d_in[2 + i];
        Wb1[i] = (const float*)d_in[10 + i];
        Wb2[i] = (const float*)d_in[18 + i];
    }
    float* out = (float*)d_out;

    char* ws = (char*)d_ws;
    const size_t CMAX = 112;
    size_t off = 0;
    float*          q  = (float*)(ws + off);          off += (size_t)NN * CMAX * 4;
    unsigned short* kv = (unsigned short*)(ws + off); off += (size_t)NN * 2 * CMAX * 2;
    float* h0          = (float*)(ws + off);          off += (size_t)NN * 64 * 4;
    float* h1          = (float*)(ws + off);          off += (size_t)NN * 64 * 4;
    int*   sorted_src  = (int*)(ws + off);            off += (size_t)NE * 4;
    int*   counts      = (int*)(ws + off);            off += (size_t)NN * 4;
    int*   offsets     = (int*)(ws + off);            off += (size_t)(NN + 1) * 4;
    int*   blocksums   = (int*)(ws + off);            off += (size_t)SCAN_NB * 4;
    int*   hist        = (int*)(ws + off);            off += (size_t)HISTN * 4;
    int*   gsums       = (int*)(ws + off);            off += (size_t)GS_NB * 4;
    int*   bstart      = (int*)(ws + off);            off += (size_t)(NBUCK + 1) * 4;
    unsigned* ebuf     = (unsigned*)(ws + off);       off += (size_t)NE * 4;
    (void)ws_size; (void)in_sizes; (void)n_in; (void)out_size;

    // ---- build CSR once: deterministic radix partition + per-bucket LDS sort ----
    bin_count<<<NBLK, 256, 0, stream>>>(ei, hist);
    gscan1<<<GS_NB, SCAN_T, 0, stream>>>(hist, gsums);
    gscan2<<<1, 256, 0, stream>>>(gsums);
    gscan3<<<(HISTN + 255) / 256, 256, 0, stream>>>(hist, gsums, bstart);
    bin_scatter<<<NBLK, 256, 0, stream>>>(ei, hist, ebuf);
    bucket_hist<<<NBUCK, 256, 0, stream>>>(bstart, ebuf, counts);
    scan1<<<SCAN_NB, SCAN_T, 0, stream>>>(counts, offsets, blocksums);
    scan2<<<1, 128, 0, stream>>>(blocksums);
    scan3<<<(NN + 255) / 256, 256, 0, stream>>>(offsets, blocksums);
    csr_write<<<NBUCK, 256, 0, stream>>>(bstart, ebuf, offsets, sorted_src);

    // ---- W pre-split (aliased into ebuf; dead after csr_write, stream-ordered) ----
    unsigned short* wspbase =
        (unsigned short*)(((uintptr_t)ebuf + 255) & ~(uintptr_t)255);
    unsigned short* wsp0 = wspbase;                  // 16 ct * 1 ks * 1024
    unsigned short* wsp1 = wsp0 + 16 * 1 * 1024;     // 16 ct * 2 ks * 1024
    unsigned short* wsp2 = wsp1 + 16 * 2 * 1024;     // 28 ct * 2 ks * 1024
    prep_w<8, 64><<<(16 * 1 * 512 + 255) / 256, 256, 0, stream>>>(
        Wb0[0], Wb0[2], Wb0[4], Wb0[6], wsp0);
    prep_w<64, 64><<<(16 * 2 * 512 + 255) / 256, 256, 0, stream>>>(
        Wb1[0], Wb1[2], Wb1[4], Wb1[6], wsp1);
    prep_w<64, 112><<<(28 * 2 * 512 + 255) / 256, 256, 0, stream>>>(
        Wb2[0], Wb2[2], Wb2[4], Wb2[6], wsp2);

    run_layer<8,  64, true >(x,  wsp0, Wb0, offsets, sorted_src, q, kv, h0,  stream);
    run_layer<64, 64, true >(h0, wsp1, Wb1, offsets, sorted_src, q, kv, h1,  stream);
    run_layer<64, 112, false>(h1, wsp2, Wb2, offsets, sorted_src, q, kv, out, stream);
}

// Round 2
// 551.671 us; speedup vs baseline: 1.1442x; 1.0074x over previous
//
#include <hip/hip_runtime.h>
#include <hip/hip_fp16.h>
#include <math.h>
#include <float.h>
#include <stdint.h>

#define NN 100000
#define NE 1600000

#define SCAN_T 256
#define SCAN_E 1024
#define SCAN_NB ((NN + SCAN_E - 1) / SCAN_E)   // 98

#define NBUCK ((NN + 255) / 256)               // 391 buckets of 256 dsts
#define EPB   4096                              // edges per binning block
#define NBLK  ((NE + EPB - 1) / EPB)            // 391 binning blocks
#define HISTN (NBUCK * NBLK)                    // 152,881
#define GS_NB ((HISTN + SCAN_E - 1) / SCAN_E)   // 150
#define BCAP  5120                              // per-bucket LDS sort capacity

typedef __attribute__((ext_vector_type(8))) short short8v;
typedef __attribute__((ext_vector_type(4))) float float4v;

// ---------------- bf16 split helpers (RNE) ----------------
__device__ __forceinline__ unsigned short f32_to_bf16_rne(float f) {
    unsigned u = __float_as_uint(f);
    u += 0x7FFFu + ((u >> 16) & 1u);
    return (unsigned short)(u >> 16);
}
__device__ __forceinline__ float bf16_to_f32(unsigned short h) {
    return __uint_as_float(((unsigned)h) << 16);
}

// ---------------- W pre-split into MFMA B-fragment layout ----------------
// layout: per (ct, ks) cell of 1024 ushort: [hi: 64 lanes x 8][lo: 64 lanes x 8]
// lane l of a wave holds B[k = ks*32 + (l>>4)*8 + j][col = ct*16 + (l&15)]
template<int K, int OUT>
__global__ __launch_bounds__(256)
void prep_w(const float* __restrict__ Wq, const float* __restrict__ Wk,
            const float* __restrict__ Wv, const float* __restrict__ Ws,
            unsigned short* __restrict__ wsp) {
    constexpr int NKS  = (K + 31) / 32;
    constexpr int OUTT = 4 * OUT;
    constexpr int NCT  = OUTT / 16;
    int idx = blockIdx.x * 256 + threadIdx.x;
    if (idx >= NCT * NKS * 512) return;
    int j    = idx & 7;
    int lane = (idx >> 3) & 63;
    int cell = idx >> 9;            // ct*NKS + ks
    int ks   = cell % NKS;
    int ct   = cell / NKS;
    int g = lane >> 4, ln = lane & 15;
    int k = ks * 32 + g * 8 + j;
    int c = ct * 16 + ln;
    int mat = c / OUT, cm = c % OUT;
    const float* W = (mat == 0) ? Wq : (mat == 1) ? Wk : (mat == 2) ? Wv : Ws;
    float f = (k < K) ? W[(size_t)k * OUT + cm] : 0.f;
    unsigned short h = f32_to_bf16_rne(f);
    float resid = f - bf16_to_f32(h);
    wsp[(size_t)cell * 1024 + lane * 8 + j]       = h;
    wsp[(size_t)cell * 1024 + 512 + lane * 8 + j] = f32_to_bf16_rne(resid);
}

// ---------------- fused linear via bf16x3 MFMA ----------------
// Y[N x 4*OUT] = X[N x K] @ [Wq|Wk|Wv|Ws] + bias, routed to q (f32), kv (f16
// packed, INTERLEAVED: per 4-channel group [k0..k3 v0..v3]), outskip (f32).
template<int K, int OUT, int CTSPLIT>
__global__ __launch_bounds__(256)
void gemm_qkvs(const float* __restrict__ x,
               const unsigned short* __restrict__ wsp,
               const float* __restrict__ bq, const float* __restrict__ bk,
               const float* __restrict__ bv, const float* __restrict__ bs,
               float* __restrict__ q, unsigned short* __restrict__ kv,
               float* __restrict__ outskip) {
    constexpr int NKS  = (K + 31) / 32;
    constexpr int OUTT = 4 * OUT;
    constexpr int NCT  = OUTT / 16;
    constexpr int CTPB = NCT / CTSPLIT;

    const int t    = threadIdx.x;
    const int lane = t & 63;
    const int wv   = t >> 6;
    const int g    = lane >> 4;
    const int ln   = lane & 15;
    const int rowbase = (blockIdx.x * 4 + wv) * 32;
    if (rowbase >= NN) return;    // no barriers in this kernel

    union F8 { short8v v; unsigned short s[8]; uint4 u4; };

    // ---- load + split A fragments: 2 row-tiles of 16, K along lane>>4 ----
    F8 ahi[2][NKS], alo[2][NKS];
#pragma unroll
    for (int rt = 0; rt < 2; ++rt) {
        int r = rowbase + rt * 16 + ln;
        if (r >= NN) r = NN - 1;                 // stores are guarded
        const float* rowp = x + (size_t)r * K;
#pragma unroll
        for (int ks = 0; ks < NKS; ++ks) {
            const int k0 = ks * 32 + g * 8;
            float xv[8];
            if (k0 + 8 <= K) {
                float4 p0 = *(const float4*)(rowp + k0);
                float4 p1 = *(const float4*)(rowp + k0 + 4);
                xv[0] = p0.x; xv[1] = p0.y; xv[2] = p0.z; xv[3] = p0.w;
                xv[4] = p1.x; xv[5] = p1.y; xv[6] = p1.z; xv[7] = p1.w;
            } else {
#pragma unroll
                for (int j = 0; j < 8; ++j) xv[j] = 0.f;   // K=8 zero-pad
            }
#pragma unroll
            for (int j = 0; j < 8; ++j) {
                unsigned short h = f32_to_bf16_rne(xv[j]);
                ahi[rt][ks].s[j] = h;
                alo[rt][ks].s[j] = f32_to_bf16_rne(xv[j] - bf16_to_f32(h));
            }
        }
    }

    const int ct0 = blockIdx.y * CTPB;
#pragma unroll 1
    for (int ct = ct0; ct < ct0 + CTPB; ++ct) {
        // ---- B fragments: coalesced 16B/lane, L1-resident across blocks ----
        F8 bhi[NKS], blo[NKS];
        const unsigned short* wp = wsp + (size_t)(ct * NKS) * 1024 + lane * 8;
#pragma unroll
        for (int ks = 0; ks < NKS; ++ks) {
            bhi[ks].u4 = *(const uint4*)(wp + ks * 1024);
            blo[ks].u4 = *(const uint4*)(wp + ks * 1024 + 512);
        }

        const int cb  = ct * 16;
        const int mat = cb / OUT;                // wave-uniform
        const int cm  = (cb % OUT) + ln;
        const float* B = (mat == 0) ? bq : (mat == 1) ? bk : (mat == 2) ? bv : bs;
        const float bias = B[cm];
        float4v acc0 = {bias, bias, bias, bias};
        float4v acc1 = {bias, bias, bias, bias};
#pragma unroll
        for (int ks = 0; ks < NKS; ++ks) {
            acc0 = __builtin_amdgcn_mfma_f32_16x16x32_bf16(ahi[0][ks].v, blo[ks].v, acc0, 0, 0, 0);
            acc0 = __builtin_amdgcn_mfma_f32_16x16x32_bf16(alo[0][ks].v, bhi[ks].v, acc0, 0, 0, 0);
            acc0 = __builtin_amdgcn_mfma_f32_16x16x32_bf16(ahi[0][ks].v, bhi[ks].v, acc0, 0, 0, 0);
            acc1 = __builtin_amdgcn_mfma_f32_16x16x32_bf16(ahi[1][ks].v, blo[ks].v, acc1, 0, 0, 0);
            acc1 = __builtin_amdgcn_mfma_f32_16x16x32_bf16(alo[1][ks].v, bhi[ks].v, acc1, 0, 0, 0);
            acc1 = __builtin_amdgcn_mfma_f32_16x16x32_bf16(ahi[1][ks].v, bhi[ks].v, acc1, 0, 0, 0);
        }

        // ---- epilogue: D row = (lane>>4)*4 + reg, col = lane&15 (HW-verified) ----
        if (mat == 0 || mat == 3) {
            float* dst = (mat == 0) ? q : outskip;
#pragma unroll
            for (int rt = 0; rt < 2; ++rt) {
                float4v a = rt ? acc1 : acc0;
#pragma unroll
                for (int reg = 0; reg < 4; ++reg) {
                    int node = rowbase + rt * 16 + g * 4 + reg;
                    if (node < NN)
                        dst[(size_t)node * OUT + cm] = a[reg];
                }
            }
        } else {
            // interleaved kv: channel c -> (c>>2)*8 + (c&3) + (k?0:4)
            const int base = (mat == 1) ? 0 : 4;
            const int kvoff = ((cm >> 2) * 8) + (cm & 3) + base;
#pragma unroll
            for (int rt = 0; rt < 2; ++rt) {
                float4v a = rt ? acc1 : acc0;
#pragma unroll
                for (int reg = 0; reg < 4; ++reg) {
                    int node = rowbase + rt * 16 + g * 4 + reg;
                    float f = a[reg];
                    float other = __shfl_xor(f, 1);  // pair adjacent columns
                    if (node < NN && !(ln & 1)) {
                        unsigned lo16 = __half_as_ushort(__float2half_rn(f));
                        unsigned hi16 = __half_as_ushort(__float2half_rn(other));
                        *(unsigned*)(kv + (size_t)node * (2 * OUT) + kvoff)
                            = lo16 | (hi16 << 16);
                    }
                }
            }
        }
    }
}

// ---------------- deterministic radix partition by dst>>8 (unchanged) ----------------
__global__ __launch_bounds__(256)
void bin_count(const int* __restrict__ ei, int* __restrict__ hist) {
    __shared__ int h[NBUCK];
    const int t = threadIdx.x;
    for (int i = t; i < NBUCK; i += 256) h[i] = 0;
    __syncthreads();
    int e0 = blockIdx.x * EPB;
    int e1 = e0 + EPB < NE ? e0 + EPB : NE;
    for (int i = e0 + t; i < e1; i += 256)
        atomicAdd(&h[ei[NE + i] >> 8], 1);
    __syncthreads();
    for (int i = t; i < NBUCK; i += 256)
        hist[(size_t)i * NBLK + blockIdx.x] = h[i];
}

__global__ __launch_bounds__(SCAN_T)
void gscan1(int* __restrict__ a, int* __restrict__ bsums) {
    __shared__ int lds[SCAN_T];
    int t = threadIdx.x;
    int base = blockIdx.x * SCAN_E + t * 4;
    int vals[4];
    int s = 0;
#pragma unroll
    for (int j = 0; j < 4; ++j) {
        int idx = base + j;
        vals[j] = (idx < HISTN) ? a[idx] : 0;
        s += vals[j];
    }
    lds[t] = s;
    __syncthreads();
    for (int off = 1; off < SCAN_T; off <<= 1) {
        int xx = (t >= off) ? lds[t - off] : 0;
        __syncthreads();
        lds[t] += xx;
        __syncthreads();
    }
    int run = (t > 0) ? lds[t - 1] : 0;
    if (t == SCAN_T - 1) bsums[blockIdx.x] = lds[t];
#pragma unroll
    for (int j = 0; j < 4; ++j) {
        int idx = base + j;
        if (idx < HISTN) a[idx] = run;
        run += vals[j];
    }
}

__global__ __launch_bounds__(256)
void gscan2(int* __restrict__ bsums) {
    __shared__ int lds[256];
    int t = threadIdx.x;
    lds[t] = (t < GS_NB) ? bsums[t] : 0;
    __syncthreads();
    for (int off = 1; off < 256; off <<= 1) {
        int xx = (t >= off) ? lds[t - off] : 0;
        __syncthreads();
        lds[t] += xx;
        __syncthreads();
    }
    if (t < GS_NB) bsums[t] = (t > 0) ? lds[t - 1] : 0;
}

__global__ __launch_bounds__(256)
void gscan3(int* __restrict__ a, const int* __restrict__ bsums,
            int* __restrict__ bstart) {
    int i = blockIdx.x * 256 + threadIdx.x;
    if (i < HISTN) {
        int v = a[i] + bsums[i / SCAN_E];
        a[i] = v;
        if (i % NBLK == 0) bstart[i / NBLK] = v;
    }
    if (i == 0) bstart[NBUCK] = NE;
}

__global__ __launch_bounds__(256)
void bin_scatter(const int* __restrict__ ei, const int* __restrict__ hist,
                 unsigned* __restrict__ ebuf) {
    __shared__ int off[NBUCK];
    const int t = threadIdx.x;
    for (int i = t; i < NBUCK; i += 256)
        off[i] = hist[(size_t)i * NBLK + blockIdx.x];
    __syncthreads();
    int e0 = blockIdx.x * EPB;
    int e1 = e0 + EPB < NE ? e0 + EPB : NE;
    for (int i = e0 + t; i < e1; i += 256) {
        int src = ei[i];
        int dst = ei[NE + i];
        int b = dst >> 8;
        int p = atomicAdd(&off[b], 1);
        ebuf[p] = ((unsigned)(dst & 255) << 17) | (unsigned)src;
    }
}

__global__ __launch_bounds__(256)
void bucket_hist(const int* __restrict__ bstart,
                 const unsigned* __restrict__ ebuf,
                 int* __restrict__ counts) {
    __shared__ int h[256];
    const int b = blockIdx.x;
    const int t = threadIdx.x;
    h[t] = 0;
    __syncthreads();
    int beg = bstart[b], end = bstart[b + 1];
    for (int i = beg + t; i < end; i += 256)
        atomicAdd(&h[ebuf[i] >> 17], 1);
    __syncthreads();
    int d = b * 256 + t;
    if (d < NN) counts[d] = h[t];
}

__global__ __launch_bounds__(SCAN_T)
void scan1(const int* __restrict__ counts, int* __restrict__ offsets,
           int* __restrict__ blocksums) {
    __shared__ int lds[SCAN_T];
    int t = threadIdx.x;
    int base = blockIdx.x * SCAN_E + t * 4;
    int vals[4];
    int s = 0;
#pragma unroll
    for (int j = 0; j < 4; ++j) {
        int idx = base + j;
        vals[j] = (idx < NN) ? counts[idx] : 0;
        s += vals[j];
    }
    lds[t] = s;
    __syncthreads();
    for (int off = 1; off < SCAN_T; off <<= 1) {
        int xx = (t >= off) ? lds[t - off] : 0;
        __syncthreads();
        lds[t] += xx;
        __syncthreads();
    }
    int run = (t > 0) ? lds[t - 1] : 0;
    if (t == SCAN_T - 1) blocksums[blockIdx.x] = lds[t];
#pragma unroll
    for (int j = 0; j < 4; ++j) {
        int idx = base + j;
        if (idx < NN) offsets[idx] = run;
        run += vals[j];
    }
}

__global__ __launch_bounds__(128)
void scan2(int* __restrict__ blocksums) {
    __shared__ int lds[128];
    int t = threadIdx.x;
    lds[t] = (t < SCAN_NB) ? blocksums[t] : 0;
    __syncthreads();
    for (int off = 1; off < 128; off <<= 1) {
        int xx = (t >= off) ? lds[t - off] : 0;
        __syncthreads();
        lds[t] += xx;
        __syncthreads();
    }
    if (t < SCAN_NB) blocksums[t] = (t > 0) ? lds[t - 1] : 0;
}

__global__ __launch_bounds__(256)
void scan3(int* __restrict__ offsets, const int* __restrict__ blocksums) {
    int i = blockIdx.x * blockDim.x + threadIdx.x;
    if (i < NN) offsets[i] = offsets[i] + blocksums[i / SCAN_E];
    if (i == 0) offsets[NN] = NE;
}

__global__ __launch_bounds__(256)
void csr_write(const int* __restrict__ bstart,
               const unsigned* __restrict__ ebuf,
               const int* __restrict__ offsets,
               int* __restrict__ sorted_src) {
    __shared__ int h[256];
    __shared__ int pre[256];
    __shared__ int posi[256];
    __shared__ unsigned srt[BCAP];
    const int b = blockIdx.x;
    const int t = threadIdx.x;
    h[t] = 0;
    __syncthreads();
    int beg = bstart[b];
    int cnt = bstart[b + 1] - beg;
    cnt = cnt < BCAP ? cnt : BCAP;
    const unsigned* buf = ebuf + beg;
    for (int i = t; i < cnt; i += 256)
        atomicAdd(&h[buf[i] >> 17], 1);
    __syncthreads();
    int v = h[t];
    pre[t] = v;
    __syncthreads();
    for (int off = 1; off < 256; off <<= 1) {
        int xx = (t >= off) ? pre[t - off] : 0;
        __syncthreads();
        pre[t] += xx;
        __syncthreads();
    }
    posi[t] = pre[t] - v;
    __syncthreads();
    for (int i = t; i < cnt; i += 256) {
        unsigned u = buf[i];
        int dl = u >> 17;
        int p = atomicAdd(&posi[dl], 1);
        srt[p] = u & 0x1FFFFu;
    }
    __syncthreads();
    const int base = offsets[b << 8];
    for (int i = t; i < cnt; i += 256)
        sorted_src[base + i] = (int)srt[i];
}

// ---- 16-lane row sum via DPP rotates ----
__device__ __forceinline__ float row16_sum(float x) {
    int y;
    y = __builtin_amdgcn_update_dpp(0, __float_as_int(x), 0x121, 0xF, 0xF, true); x += __int_as_float(y);
    y = __builtin_amdgcn_update_dpp(0, __float_as_int(x), 0x122, 0xF, 0xF, true); x += __int_as_float(y);
    y = __builtin_amdgcn_update_dpp(0, __float_as_int(x), 0x124, 0xF, 0xF, true); x += __int_as_float(y);
    y = __builtin_amdgcn_update_dpp(0, __float_as_int(x), 0x128, 0xF, 0xF, true); x += __int_as_float(y);
    return x;
}

__device__ __forceinline__ float4 h4_to_f4(unsigned wx, unsigned wy) {
    union { unsigned u; __half2 h; } a, b;
    a.u = wx; b.u = wy;
    float2 f0 = __half22float2(a.h);
    float2 f1 = __half22float2(b.h);
    return make_float4(f0.x, f0.y, f1.x, f1.y);
}

// ---------------- fused attention gather ----------------
// interleaved kv + depth-2 rotating prefetch + exp2-domain softmax
template<int C, bool RELU>
__global__ __launch_bounds__(256)
void attn_gather(const int* __restrict__ offsets,
                 const int* __restrict__ sorted_src,
                 const float* __restrict__ q,
                 const unsigned short* __restrict__ kv,
                 float* __restrict__ out, float scale) {
    const int wid  = (int)((blockIdx.x * blockDim.x + threadIdx.x) >> 6);
    const int lane = threadIdx.x & 63;
    if (wid >= NN) return;
    const int grp = lane >> 4;
    const int ch  = (lane & 15) * 4;
    constexpr bool P2 = (C > 64);
    const bool hi = P2 && (ch + 64 < C);

    const int beg = offsets[wid], end = offsets[wid + 1];

    const float sl = scale * 1.44269504f;   // fold scale + log2(e) into q
    float4 qv0 = *(const float4*)(q + (size_t)wid * C + ch);
    qv0.x *= sl; qv0.y *= sl; qv0.z *= sl; qv0.w *= sl;
    float4 qv1 = make_float4(0.f, 0.f, 0.f, 0.f);
    if (hi) {
        qv1 = *(const float4*)(q + (size_t)wid * C + ch + 64);
        qv1.x *= sl; qv1.y *= sl; qv1.z *= sl; qv1.w *= sl;
    }

    float m = -FLT_MAX, l = 0.f;
    float4 a0 = make_float4(0.f, 0.f, 0.f, 0.f);
    float4 a1 = make_float4(0.f, 0.f, 0.f, 0.f);

    const uint4 zz = make_uint4(0, 0, 0, 0);
    uint4 A0 = zz, A1 = zz, B0 = zz, B1 = zz;

    int i = beg + grp;
    if (i < end) {
        const unsigned short* row = kv + (size_t)sorted_src[i] * (2 * C);
        A0 = *(const uint4*)(row + 2 * ch);
        if (hi) A1 = *(const uint4*)(row + 2 * ch + 128);
    }
    if (i + 4 < end) {
        const unsigned short* row = kv + (size_t)sorted_src[i + 4] * (2 * C);
        B0 = *(const uint4*)(row + 2 * ch);
        if (hi) B1 = *(const uint4*)(row + 2 * ch + 128);
    }

    while (i < end) {
        uint4 N0 = zz, N1 = zz;
        int ip = i + 8;
        if (ip < end) {
            const unsigned short* row = kv + (size_t)sorted_src[ip] * (2 * C);
            N0 = *(const uint4*)(row + 2 * ch);
            if (hi) N1 = *(const uint4*)(row + 2 * ch + 128);
        }
        // uint4 = [k0 k1 | k2 k3 | v0 v1 | v2 v3] halves for channels ch..ch+3
        float4 kf0 = h4_to_f4(A0.x, A0.y);
        float4 vf0 = h4_to_f4(A0.z, A0.w);
        float part = qv0.x * kf0.x + qv0.y * kf0.y + qv0.z * kf0.z + qv0.w * kf0.w;
        float4 vf1 = make_float4(0.f, 0.f, 0.f, 0.f);
        if (P2) {
            float4 kf1 = h4_to_f4(A1.x, A1.y);
            vf1 = h4_to_f4(A1.z, A1.w);
            part += qv1.x * kf1.x + qv1.y * kf1.y + qv1.z * kf1.z + qv1.w * kf1.w;
        }
        float s = row16_sum(part);                    // log2-domain score
        float mn = fmaxf(m, s);
        float al = __builtin_amdgcn_exp2f(m - mn);
        float w  = __builtin_amdgcn_exp2f(s - mn);
        l = l * al + w;
        a0.x = a0.x * al + w * vf0.x; a0.y = a0.y * al + w * vf0.y;
        a0.z = a0.z * al + w * vf0.z; a0.w = a0.w * al + w * vf0.w;
        if (P2) {
            a1.x = a1.x * al + w * vf1.x; a1.y = a1.y * al + w * vf1.y;
            a1.z = a1.z * al + w * vf1.z; a1.w = a1.w * al + w * vf1.w;
        }
        m = mn;
        A0 = B0; A1 = B1; B0 = N0; B1 = N1;           // rotate (static idx)
        i += 4;
    }

    // merge the 4 groups: butterfly over lane-xor 16, 32
#pragma unroll
    for (int d = 16; d <= 32; d <<= 1) {
        float mo = __shfl_xor(m, d);
        float lo = __shfl_xor(l, d);
        float4 ao0, ao1;
        ao0.x = __shfl_xor(a0.x, d); ao0.y = __shfl_xor(a0.y, d);
        ao0.z = __shfl_xor(a0.z, d); ao0.w = __shfl_xor(a0.w, d);
        if (P2) {
            ao1.x = __shfl_xor(a1.x, d); ao1.y = __shfl_xor(a1.y, d);
            ao1.z = __shfl_xor(a1.z, d); ao1.w = __shfl_xor(a1.w, d);
        }
        float mn = fmaxf(m, mo);
        float e1 = (l  > 0.f) ? __builtin_amdgcn_exp2f(m  - mn) : 0.f;
        float e2 = (lo > 0.f) ? __builtin_amdgcn_exp2f(mo - mn) : 0.f;
        l = l * e1 + lo * e2;
        a0.x = a0.x * e1 + ao0.x * e2; a0.y = a0.y * e1 + ao0.y * e2;
        a0.z = a0.z * e1 + ao0.z * e2; a0.w = a0.w * e1 + ao0.w * e2;
        if (P2) {
            a1.x = a1.x * e1 + ao1.x * e2; a1.y = a1.y * e1 + ao1.y * e2;
            a1.z = a1.z * e1 + ao1.z * e2; a1.w = a1.w * e1 + ao1.w * e2;
        }
        m = mn;
    }

    if (lane < 16) {
        float inv = (l > 0.f) ? 1.f / l : 0.f;
        size_t o = (size_t)wid * C + ch;
        float4 sk = *(const float4*)(out + o);
        float4 r;
        r.x = sk.x + a0.x * inv; r.y = sk.y + a0.y * inv;
        r.z = sk.z + a0.z * inv; r.w = sk.w + a0.w * inv;
        if (RELU) {
            r.x = fmaxf(r.x, 0.f); r.y = fmaxf(r.y, 0.f);
            r.z = fmaxf(r.z, 0.f); r.w = fmaxf(r.w, 0.f);
        }
        *(float4*)(out + o) = r;
        if (hi) {
            float4 sk1 = *(const float4*)(out + o + 64);
            float4 r1;
            r1.x = sk1.x + a1.x * inv; r1.y = sk1.y + a1.y * inv;
            r1.z = sk1.z + a1.z * inv; r1.w = sk1.w + a1.w * inv;
            if (RELU) {
                r1.x = fmaxf(r1.x, 0.f); r1.y = fmaxf(r1.y, 0.f);
                r1.z = fmaxf(r1.z, 0.f); r1.w = fmaxf(r1.w, 0.f);
            }
            *(float4*)(out + o + 64) = r1;
        }
    }
}

// ---------------- host side ----------------
template<int K, int OUT, bool RELU>
static void run_layer(const float* xin, const unsigned short* wsp,
                      const float* const* Wb,
                      const int* offsets, const int* sorted_src,
                      float* q, unsigned short* kv,
                      float* out, hipStream_t stream) {
    constexpr int CTSPLIT = 2;
    dim3 gg((NN + 127) / 128, CTSPLIT);
    gemm_qkvs<K, OUT, CTSPLIT><<<gg, 256, 0, stream>>>(
        xin, wsp, Wb[1], Wb[3], Wb[5], Wb[7], q, kv, out);

    float scale = 1.0f / sqrtf((float)OUT);
    attn_gather<OUT, RELU><<<(NN + 3) / 4, 256, 0, stream>>>(
        offsets, sorted_src, q, kv, out, scale);
}

extern "C" void kernel_launch(void* const* d_in, const int* in_sizes, int n_in,
                              void* d_out, int out_size, void* d_ws, size_t ws_size,
                              hipStream_t stream) {
    const float* x  = (const float*)d_in[0];
    const int*   ei = (const int*)d_in[1];
    const float* Wb0[8], *Wb1[8], *Wb2[8];
    for (int i = 0; i < 8; ++i) {
        Wb0[i] = (const float*)d_in[2 + i];
        Wb1[i] = (const float*)d_in[10 + i];
        Wb2[i] = (const float*)d_in[18 + i];
    }
    float* out = (float*)d_out;

    char* ws = (char*)d_ws;
    const size_t CMAX = 112;
    size_t off = 0;
    float*          q  = (float*)(ws + off);          off += (size_t)NN * CMAX * 4;
    unsigned short* kv = (unsigned short*)(ws + off); off += (size_t)NN * 2 * CMAX * 2;
    float* h0          = (float*)(ws + off);          off += (size_t)NN * 64 * 4;
    float* h1          = (float*)(ws + off);          off += (size_t)NN * 64 * 4;
    int*   sorted_src  = (int*)(ws + off);            off += (size_t)NE * 4;
    int*   counts      = (int*)(ws + off);            off += (size_t)NN * 4;
    int*   offsets     = (int*)(ws + off);            off += (size_t)(NN + 1) * 4;
    int*   blocksums   = (int*)(ws + off);            off += (size_t)SCAN_NB * 4;
    int*   hist        = (int*)(ws + off);            off += (size_t)HISTN * 4;
    int*   gsums       = (int*)(ws + off);            off += (size_t)GS_NB * 4;
    int*   bstart      = (int*)(ws + off);            off += (size_t)(NBUCK + 1) * 4;
    unsigned* ebuf     = (unsigned*)(ws + off);       off += (size_t)NE * 4;
    (void)ws_size; (void)in_sizes; (void)n_in; (void)out_size;

    // ---- build CSR once: deterministic radix partition + per-bucket LDS sort ----
    bin_count<<<NBLK, 256, 0, stream>>>(ei, hist);
    gscan1<<<GS_NB, SCAN_T, 0, stream>>>(hist, gsums);
    gscan2<<<1, 256, 0, stream>>>(gsums);
    gscan3<<<(HISTN + 255) / 256, 256, 0, stream>>>(hist, gsums, bstart);
    bin_scatter<<<NBLK, 256, 0, stream>>>(ei, hist, ebuf);
    bucket_hist<<<NBUCK, 256, 0, stream>>>(bstart, ebuf, counts);
    scan1<<<SCAN_NB, SCAN_T, 0, stream>>>(counts, offsets, blocksums);
    scan2<<<1, 128, 0, stream>>>(blocksums);
    scan3<<<(NN + 255) / 256, 256, 0, stream>>>(offsets, blocksums);
    csr_write<<<NBUCK, 256, 0, stream>>>(bstart, ebuf, offsets, sorted_src);

    // ---- W pre-split (aliased into ebuf; dead after csr_write, stream-ordered) ----
    unsigned short* wspbase =
        (unsigned short*)(((uintptr_t)ebuf + 255) & ~(uintptr_t)255);
    unsigned short* wsp0 = wspbase;                  // 16 ct * 1 ks * 1024
    unsigned short* wsp1 = wsp0 + 16 * 1 * 1024;     // 16 ct * 2 ks * 1024
    unsigned short* wsp2 = wsp1 + 16 * 2 * 1024;     // 28 ct * 2 ks * 1024
    prep_w<8, 64><<<(16 * 1 * 512 + 255) / 256, 256, 0, stream>>>(
        Wb0[0], Wb0[2], Wb0[4], Wb0[6], wsp0);
    prep_w<64, 64><<<(16 * 2 * 512 + 255) / 256, 256, 0, stream>>>(
        Wb1[0], Wb1[2], Wb1[4], Wb1[6], wsp1);
    prep_w<64, 112><<<(28 * 2 * 512 + 255) / 256, 256, 0, stream>>>(
        Wb2[0], Wb2[2], Wb2[4], Wb2[6], wsp2);

    run_layer<8,  64, true >(x,  wsp0, Wb0, offsets, sorted_src, q, kv, h0,  stream);
    run_layer<64, 64, true >(h0, wsp1, Wb1, offsets, sorted_src, q, kv, h1,  stream);
    run_layer<64, 112, false>(h1, wsp2, Wb2, offsets, sorted_src, q, kv, out, stream);
}